// Round 1
// baseline (730.130 us; speedup 1.0000x reference)
//
#include <hip/hip_runtime.h>
#include <hip/hip_bf16.h>
#include <stdint.h>

// ---------------------------------------------------------------------------
// PytorchLlamaSDPA: GQA attention (64 q-heads, 8 kv-heads, S=KV=2048, D=128)
// + additive mask (s,t) + softmax + PV + output projection (8192x8192^T).
// Strategy: convert to bf16, MFMA 16x16x32 everywhere, fp32 softmax/accum.
// ---------------------------------------------------------------------------

typedef __bf16 bf16;
typedef __attribute__((ext_vector_type(8))) __bf16 bf16x8;
typedef __attribute__((ext_vector_type(4))) __bf16 bf16x4;
typedef __attribute__((ext_vector_type(4))) float f32x4;

#define N_HEADS 64
#define N_KVH   8
#define HDIM    128
#define SEQ     2048
#define KVL     2048
#define DIM     8192

// global->LDS direct load, 16B per lane. LDS dest must be wave-uniform base;
// HW writes at base + lane*16. Global src is per-lane (lets us pre-swizzle).
__device__ __forceinline__ void gload16(const void* g, void* l) {
  __builtin_amdgcn_global_load_lds((const __attribute__((address_space(1))) void*)g,
                                   (__attribute__((address_space(3))) void*)l,
                                   16, 0, 0);
}

// --------------------------- fp32 -> bf16 (flat) ---------------------------
__global__ void cvt_f32_bf16(const float* __restrict__ in, bf16* __restrict__ out, int n4) {
  int i = blockIdx.x * blockDim.x + threadIdx.x;
  int stride = gridDim.x * blockDim.x;
  for (; i < n4; i += stride) {
    float4 v = ((const float4*)in)[i];
    bf16x4 o = { (bf16)v.x, (bf16)v.y, (bf16)v.z, (bf16)v.w };
    *(bf16x4*)(out + (long)i * 4) = o;
  }
}

// ------------------- values (kh,t,d) -> bf16 V^T (kh,d,t) ------------------
__global__ void cvt_vT_kernel(const float* __restrict__ v, bf16* __restrict__ vT) {
  __shared__ bf16 tile[64][132];   // +4 pad breaks bank aliasing on transpose read
  const int tid = threadIdx.x;
  const int kh = blockIdx.x >> 5;
  const int t0 = (blockIdx.x & 31) << 6;
  const float* src = v + ((long)kh * KVL + t0) * HDIM;
#pragma unroll
  for (int it = 0; it < 8; ++it) {
    int q = it * 256 + tid;
    int r = q >> 5;
    int c4 = (q & 31) << 2;
    float4 val = *(const float4*)(src + (long)r * HDIM + c4);
    bf16x4 o = { (bf16)val.x, (bf16)val.y, (bf16)val.z, (bf16)val.w };
    *(bf16x4*)&tile[r][c4] = o;
  }
  __syncthreads();
  const int t = tid & 63;
  const int dbase = tid >> 6;
#pragma unroll
  for (int it = 0; it < 32; ++it) {
    int d = it * 4 + dbase;
    vT[((long)kh * HDIM + d) * KVL + t0 + t] = tile[t][d];
  }
}

// ------------------------------- attention ---------------------------------
// Block = (head h, 64 q-rows). 4 waves, wave w owns q-rows [w*16, w*16+16).
// KV tiles of 64. LDS layouts (all XOR-chunk-swizzled, 16B chunk granularity):
//   Qlds[64][128] bf16 (256B rows, chunk c stores global chunk c^(row&7))
//   Klds[64][128] bf16 (same swizzle)
//   Vlds[128][64] bf16 (V^T: row=d 128B rows, chunk c stores c^(d&7))
//   Plds: per-wave 16x64 bf16 (128B rows, swizzled) for P->A-frag roundtrip.
__global__ __launch_bounds__(256, 2) void attn_kernel(
    const bf16* __restrict__ qB, const bf16* __restrict__ kB,
    const bf16* __restrict__ vT, const float* __restrict__ mask,
    bf16* __restrict__ attnB)
{
  __shared__ __align__(16) bf16 Qlds[64 * 128];
  __shared__ __align__(16) bf16 Klds[64 * 128];
  __shared__ __align__(16) bf16 Vlds[128 * 64];
  __shared__ __align__(16) bf16 Plds[4 * 16 * 64];

  const int tid = threadIdx.x;
  const int lane = tid & 63;
  const int w = tid >> 6;

  // XCD-aware swizzle (2048 % 8 == 0 -> bijective): cluster same-q0 blocks per XCD
  const int swz = (blockIdx.x & 7) * 256 + (blockIdx.x >> 3);
  const int h  = swz & 63;
  const int q0 = (swz >> 6) << 6;
  const int kh = h >> 3;

  // ---- stage Q (once) ----
#pragma unroll
  for (int i = 0; i < 4; ++i) {
    int seg = w * 4 + i;
    int m = seg * 4 + (lane >> 4);
    int c = lane & 15;
    const bf16* g = qB + ((long)(q0 + m) * N_HEADS + h) * HDIM + ((c ^ (m & 7)) << 3);
    gload16(g, (char*)Qlds + seg * 1024);
  }
  __syncthreads();

  bf16x8 qf[4];
  {
    int m = w * 16 + (lane & 15);
#pragma unroll
    for (int kc = 0; kc < 4; ++kc) {
      int c = kc * 4 + (lane >> 4);
      qf[kc] = *(const bf16x8*)((const char*)Qlds + m * 256 + ((c ^ (m & 7)) << 4));
    }
  }

  float mreg[4], lreg[4];
  f32x4 acc_o[8];
  const f32x4 zero4 = { 0.f, 0.f, 0.f, 0.f };
#pragma unroll
  for (int r = 0; r < 4; ++r) { mreg[r] = -1e30f; lreg[r] = 0.f; }
#pragma unroll
  for (int nt = 0; nt < 8; ++nt) acc_o[nt] = zero4;

  const float scale = 0.08838834764831845f;  // 1/sqrt(128)
  const float* mrow = mask + (long)(q0 + w * 16 + ((lane >> 4) << 2)) * KVL + (lane & 15);

  for (int kt = 0; kt < KVL / 64; ++kt) {
    const int kv0 = kt * 64;
    // ---- stage K tile ----
#pragma unroll
    for (int i = 0; i < 4; ++i) {
      int seg = w * 4 + i;
      int rr = seg * 4 + (lane >> 4);
      int c = lane & 15;
      const bf16* g = kB + ((long)kh * KVL + kv0 + rr) * HDIM + ((c ^ (rr & 7)) << 3);
      gload16(g, (char*)Klds + seg * 1024);
    }
    // ---- stage V^T tile ----
#pragma unroll
    for (int i = 0; i < 4; ++i) {
      int seg = w * 4 + i;
      int d = seg * 8 + (lane >> 3);
      int c = lane & 7;
      const bf16* g = vT + ((long)kh * HDIM + d) * KVL + kv0 + ((c ^ (d & 7)) << 3);
      gload16(g, (char*)Vlds + seg * 1024);
    }
    // ---- mask loads (overlap with staging; drained by barrier) ----
    float mk[4][4];
#pragma unroll
    for (int r = 0; r < 4; ++r)
#pragma unroll
      for (int n = 0; n < 4; ++n)
        mk[n][r] = mrow[(long)r * KVL + kv0 + n * 16];
    __syncthreads();

    // ---- QK^T: S(16x64) per wave ----
    f32x4 acc_s[4];
#pragma unroll
    for (int n = 0; n < 4; ++n) acc_s[n] = zero4;
#pragma unroll
    for (int kc = 0; kc < 4; ++kc) {
#pragma unroll
      for (int n = 0; n < 4; ++n) {
        int rrow = n * 16 + (lane & 15);
        int c = kc * 4 + (lane >> 4);
        bf16x8 kf = *(const bf16x8*)((const char*)Klds + rrow * 256 + ((c ^ (rrow & 7)) << 4));
        acc_s[n] = __builtin_amdgcn_mfma_f32_16x16x32_bf16(qf[kc], kf, acc_s[n], 0, 0, 0);
      }
    }

    // ---- online softmax (fp32). Row r lives in 16-lane group; wave-parallel. ----
    float pv[4][4];
#pragma unroll
    for (int n = 0; n < 4; ++n)
#pragma unroll
      for (int r = 0; r < 4; ++r)
        pv[n][r] = acc_s[n][r] * scale + mk[n][r];

#pragma unroll
    for (int r = 0; r < 4; ++r) {
      float mx = fmaxf(fmaxf(pv[0][r], pv[1][r]), fmaxf(pv[2][r], pv[3][r]));
      mx = fmaxf(mx, __shfl_xor(mx, 1));
      mx = fmaxf(mx, __shfl_xor(mx, 2));
      mx = fmaxf(mx, __shfl_xor(mx, 4));
      mx = fmaxf(mx, __shfl_xor(mx, 8));
      float newm = fmaxf(mreg[r], mx);
      float al = __expf(mreg[r] - newm);
      mreg[r] = newm;
      float ps = 0.f;
#pragma unroll
      for (int n = 0; n < 4; ++n) { pv[n][r] = __expf(pv[n][r] - newm); ps += pv[n][r]; }
      lreg[r] = lreg[r] * al + ps;   // per-lane partial (4 cols); reduced at end
#pragma unroll
      for (int nt = 0; nt < 8; ++nt) acc_o[nt][r] *= al;
    }

    // ---- P -> LDS (bf16, swizzled), wave-private ----
    char* pbase = (char*)Plds + w * 2048;
#pragma unroll
    for (int r = 0; r < 4; ++r) {
      int rr2 = ((lane >> 4) << 2) + r;
#pragma unroll
      for (int n = 0; n < 4; ++n) {
        int off = rr2 * 128 + ((n * 16 + (lane & 15)) << 1);
        *(bf16*)(pbase + (off ^ ((rr2 & 7) << 4))) = (bf16)pv[n][r];
      }
    }

    // ---- PV: O(16x128) += P(16x64) * V(64x128) ----
#pragma unroll
    for (int kc = 0; kc < 2; ++kc) {
      int pm = lane & 15;
      int c = kc * 4 + (lane >> 4);
      bf16x8 pf = *(const bf16x8*)((const char*)pbase + pm * 128 + ((c ^ (pm & 7)) << 4));
#pragma unroll
      for (int nt = 0; nt < 8; ++nt) {
        int vr = nt * 16 + (lane & 15);
        bf16x8 vf = *(const bf16x8*)((const char*)Vlds + vr * 128 + ((c ^ (vr & 7)) << 4));
        acc_o[nt] = __builtin_amdgcn_mfma_f32_16x16x32_bf16(pf, vf, acc_o[nt], 0, 0, 0);
      }
    }
    __syncthreads();   // protect K/V LDS before next stage
  }

  // ---- epilogue: finish l reduction, normalize, store bf16 ----
#pragma unroll
  for (int r = 0; r < 4; ++r) {
    float s = lreg[r];
    s += __shfl_xor(s, 1);
    s += __shfl_xor(s, 2);
    s += __shfl_xor(s, 4);
    s += __shfl_xor(s, 8);
    lreg[r] = 1.0f / s;
  }
  const int orow = q0 + w * 16 + ((lane >> 4) << 2);
#pragma unroll
  for (int r = 0; r < 4; ++r) {
    bf16* op = attnB + (long)(orow + r) * DIM + h * HDIM + (lane & 15);
#pragma unroll
    for (int nt = 0; nt < 8; ++nt)
      op[nt * 16] = (bf16)(acc_o[nt][r] * lreg[r]);
  }
}

// ------------------------------ projection GEMM ----------------------------
// C[2048x8192] = A[2048x8192] * B[8192x8192]^T, A/B bf16 row-major along k.
// 128x128 tile, BK=64, 4 waves (2x2), 4x4 16x16 fragments per wave.
__global__ __launch_bounds__(256, 2) void gemm_bt(
    const bf16* __restrict__ A, const bf16* __restrict__ B, float* __restrict__ C)
{
  __shared__ __align__(16) bf16 Alds[128 * 64];
  __shared__ __align__(16) bf16 Blds[128 * 64];
  const int tid = threadIdx.x;
  const int lane = tid & 63;
  const int w = tid >> 6;

  // bijective XCD swizzle (1024 % 8 == 0)
  const int swz = (blockIdx.x & 7) * 128 + (blockIdx.x >> 3);
  const int m0 = (swz >> 6) << 7;   // 16 m-tiles
  const int n0 = (swz & 63) << 7;   // 64 n-tiles
  const int wr = (w >> 1) << 6;
  const int wc = (w & 1) << 6;

  f32x4 acc[4][4];
  const f32x4 zero4 = { 0.f, 0.f, 0.f, 0.f };
#pragma unroll
  for (int i = 0; i < 4; ++i)
#pragma unroll
    for (int j = 0; j < 4; ++j) acc[i][j] = zero4;

  for (int kt = 0; kt < DIM / 64; ++kt) {
    const int k0 = kt * 64;
#pragma unroll
    for (int i = 0; i < 4; ++i) {
      int seg = w * 4 + i;
      int m = seg * 8 + (lane >> 3);
      int c = lane & 7;
      const bf16* ga = A + (long)(m0 + m) * DIM + k0 + ((c ^ (m & 7)) << 3);
      gload16(ga, (char*)Alds + seg * 1024);
      const bf16* gb = B + (long)(n0 + m) * DIM + k0 + ((c ^ (m & 7)) << 3);
      gload16(gb, (char*)Blds + seg * 1024);
    }
    __syncthreads();
#pragma unroll
    for (int kc = 0; kc < 2; ++kc) {
      bf16x8 af[4], bfr[4];
#pragma unroll
      for (int i = 0; i < 4; ++i) {
        int m = wr + i * 16 + (lane & 15);
        int c = kc * 4 + (lane >> 4);
        af[i] = *(const bf16x8*)((const char*)Alds + m * 128 + ((c ^ (m & 7)) << 4));
        int n = wc + i * 16 + (lane & 15);
        bfr[i] = *(const bf16x8*)((const char*)Blds + n * 128 + ((c ^ (n & 7)) << 4));
      }
#pragma unroll
      for (int i = 0; i < 4; ++i)
#pragma unroll
        for (int j = 0; j < 4; ++j)
          acc[i][j] = __builtin_amdgcn_mfma_f32_16x16x32_bf16(af[i], bfr[j], acc[i][j], 0, 0, 0);
    }
    __syncthreads();
  }

#pragma unroll
  for (int i = 0; i < 4; ++i) {
#pragma unroll
    for (int r = 0; r < 4; ++r) {
      float* cp = C + (long)(m0 + wr + i * 16 + ((lane >> 4) << 2) + r) * DIM + n0 + wc + (lane & 15);
#pragma unroll
      for (int j = 0; j < 4; ++j)
        cp[j * 16] = acc[i][j][r];
    }
  }
}

// ------------------------------- launcher ----------------------------------
extern "C" void kernel_launch(void* const* d_in, const int* in_sizes, int n_in,
                              void* d_out, int out_size, void* d_ws, size_t ws_size,
                              hipStream_t stream) {
  const float* xq     = (const float*)d_in[0];
  const float* keys   = (const float*)d_in[1];
  const float* values = (const float*)d_in[2];
  const float* mask   = (const float*)d_in[3];
  const float* wo     = (const float*)d_in[4];
  float* out = (float*)d_out;
  char* ws = (char*)d_ws;

  // workspace layout (bytes): 200 MB total
  bf16* woB = (bf16*)ws;                                   // 128 MB
  bf16* qB  = (bf16*)(ws + 134217728ull);                  //  32 MB
  bf16* kB  = (bf16*)(ws + 134217728ull + 33554432ull);    //   4 MB
  bf16* vT  = (bf16*)(ws + 134217728ull + 37748736ull);    //   4 MB
  bf16* aB  = (bf16*)(ws + 134217728ull + 41943040ull);    //  32 MB

  cvt_f32_bf16<<<dim3(2048), dim3(256), 0, stream>>>(wo, woB, 16777216);
  cvt_f32_bf16<<<dim3(1024), dim3(256), 0, stream>>>(xq, qB, 4194304);
  cvt_f32_bf16<<<dim3(256),  dim3(256), 0, stream>>>(keys, kB, 524288);
  cvt_vT_kernel<<<dim3(256), dim3(256), 0, stream>>>(values, vT);
  attn_kernel<<<dim3(2048),  dim3(256), 0, stream>>>(qB, kB, vT, mask, aB);
  gemm_bt<<<dim3(1024),      dim3(256), 0, stream>>>(aB, woB, out);
}